// Round 8
// baseline (123.350 us; speedup 1.0000x reference)
//
#include <hip/hip_runtime.h>
#include <hip/hip_fp16.h>
#include <math.h>

// B=4096, D=768, K=60. Output: scalar fp32 mean CE loss, label 0.
// loss_b = logsumexp(logits_b) - logits_b[0].
//
// Ledger: R0 103.4 / R2 104.7 (L2 plane split: null) / R3 134.8 (atomic
// queue measured 62us; gather occ 42%, VALU 15% => latency-bound) /
// R4 106.5 (sched_barrier: null) / R5 698.8 (coop: 8 waves/CU disaster)
// / R6 113.3 (LDS-DMA: -7us) / R7 103.6 (3-disp fused + padded atomics).
// Gather is ~36-40us under every per-wave issue mechanism. Last un-probed
// axes on the latency theory, both surgical:
//   (a) RESIDENT WAVES: __launch_bounds__(512, 8) -> request 8 waves/EU
//       = 32 waves/CU (R3 measured only 42% occ). VGPR cap 64 >> 36 used.
//   (b) L1 BYPASS: item gather rows have ~zero per-CU reuse (61 touches
//       GRID-wide) but thrash the 32KB L1 -> nontemporal loads skip L1
//       allocation (MSHR/eviction pressure off the TCP path).
// Structure otherwise byte-identical to R7 (best known).

#define NB 4096
#define ND 768
#define NK 60
#define ND4  (ND / 4)          // 192 float4 per fp32 row
#define NDU  (ND / 2)          // 384 uints per fp16 row
#define NLOGITS (NK + 1)       // 61
#define NPAD 64

#define NSLOT 64               // loss accumulator slots, one 64B line each

#define WS_ITEMS_OFF 0
#define WS_USER_OFF  ((size_t)NB * ND * 2)                  // +6.29 MB
#define WS_SLOTS_OFF (WS_USER_OFF + (size_t)NB * ND * 2)    // +6.29 MB
#define WS_NEED      (WS_SLOTS_OFF + (size_t)NSLOT * 16 * 4)

typedef _Float16 h2 __attribute__((ext_vector_type(2)));
typedef float    f2 __attribute__((ext_vector_type(2)));
typedef float    f4v __attribute__((ext_vector_type(4)));
typedef unsigned int u4v __attribute__((ext_vector_type(4)));
typedef unsigned int u2v __attribute__((ext_vector_type(2)));

__device__ __forceinline__ float dot2_acc(unsigned int u, unsigned int v, float c) {
#if __has_builtin(__builtin_amdgcn_fdot2)
    return __builtin_amdgcn_fdot2(__builtin_bit_cast(h2, u),
                                  __builtin_bit_cast(h2, v), c, false);
#else
    f2 a = __builtin_convertvector(__builtin_bit_cast(h2, u), f2);
    f2 b = __builtin_convertvector(__builtin_bit_cast(h2, v), f2);
    return c + a.x * b.x + a.y * b.y;
#endif
}

__device__ __forceinline__ unsigned int pack_h2(float x, float y) {
    h2 h = { (_Float16)x, (_Float16)y };
    return __builtin_bit_cast(unsigned int, h);
}

// Butterfly fold: 8 per-lane partials -> every lane holds the full 64-lane
// sum of logit (lane & 7).  (Verified: absmax 0 in rounds 0/2/3/4/5/6/7.)
__device__ __forceinline__ float fold8(const float acc[8], int lane) {
    const int bit0 = lane & 1;
    float n[4];
    #pragma unroll
    for (int j = 0; j < 4; ++j) {
        float mine  = bit0 ? acc[2*j+1] : acc[2*j];
        float other = bit0 ? acc[2*j]   : acc[2*j+1];
        n[j] = mine + __shfl_xor(other, 1, 64);
    }
    const int bit1 = (lane >> 1) & 1;
    float s[2];
    #pragma unroll
    for (int j = 0; j < 2; ++j) {
        float mine  = bit1 ? n[2*j+1] : n[2*j];
        float other = bit1 ? n[2*j]   : n[2*j+1];
        s[j] = mine + __shfl_xor(other, 2, 64);
    }
    const int bit2 = (lane >> 2) & 1;
    float mine  = bit2 ? s[1] : s[0];
    float other = bit2 ? s[0] : s[1];
    float r = mine + __shfl_xor(other, 4, 64);
    r += __shfl_xor(r, 8, 64);
    r += __shfl_xor(r, 16, 64);
    r += __shfl_xor(r, 32, 64);
    return r;
}

// ---- phase 1: items + user fp32 -> fp16; zero the slot accumulators ----
__global__ __launch_bounds__(256) void convert_all_f16(
    const f4v* __restrict__ items,
    const f4v* __restrict__ user,
    uint2* __restrict__ itemsh,
    uint2* __restrict__ userh,
    float* __restrict__ slots)
{
    const int half = NB * ND4;                  // 786432 float4 per table
    int i = blockIdx.x * 256 + threadIdx.x;

    if (blockIdx.x == 0) {
        // zero 64 padded slots (64 x 16 floats = 1024 floats)
        ((float4*)slots)[threadIdx.x] = make_float4(0.f, 0.f, 0.f, 0.f);
    }

    const f4v* src = (i < half) ? items : user;
    uint2*     dst = (i < half) ? itemsh : userh;
    int        j   = (i < half) ? i : i - half;

    f4v v = __builtin_nontemporal_load(src + j);
    uint2 rv;
    rv.x = pack_h2(v.x, v.y);
    rv.y = pack_h2(v.z, v.w);
    dst[j] = rv;
}

// ---- phase 2: one block (8 waves) per row; gather + LSE + slot atomic ----
// launch_bounds(512, 8): request 8 waves/EU -> 32 waves/CU residency.
__global__ __launch_bounds__(512, 8) void gather_lse_fused(
    const unsigned int* __restrict__ userh,
    const unsigned int* __restrict__ itemsh,
    const int* __restrict__ negidx,
    float* __restrict__ slots)
{
    const int tid  = threadIdx.x;
    const int lane = tid & 63;
    const int slot = tid >> 6;          // wave id, 0..7
    const int b    = blockIdx.x;

    // 8 row indices for this wave (wave-uniform -> scalar loads)
    const int* nrow = negidx + (size_t)b * NK;
    int rows[8];
    #pragma unroll
    for (int i = 0; i < 8; ++i) {
        int k = slot * 8 + i;
        rows[i] = (k == 0 || k > NK) ? b : nrow[k - 1];
    }

    // user row fp16 (same layout as item rows); L1-shared across 8 waves
    const unsigned int* ur = userh + (size_t)b * NDU;
    uint4 ua = ((const uint4*)ur)[lane];          // elements 8l..8l+7
    uint2 ub = ((const uint2*)(ur + 256))[lane];  // elements 512+4l..+3

    // 16 gather loads; NT -> bypass L1 allocation (no per-CU reuse)
    u4v va[8];
    u2v vb[8];
    #pragma unroll
    for (int i = 0; i < 8; ++i) {
        const unsigned int* ir = itemsh + (size_t)rows[i] * NDU;
        va[i] = __builtin_nontemporal_load((const u4v*)ir + lane);
        vb[i] = __builtin_nontemporal_load((const u2v*)(ir + 256) + lane);
    }

    float acc[8];
    #pragma unroll
    for (int i = 0; i < 8; ++i) {
        float a = 0.0f;
        a = dot2_acc(ua.x, va[i].x, a);
        a = dot2_acc(ua.y, va[i].y, a);
        a = dot2_acc(ua.z, va[i].z, a);
        a = dot2_acc(ua.w, va[i].w, a);
        a = dot2_acc(ub.x, vb[i].x, a);
        a = dot2_acc(ub.y, vb[i].y, a);
        acc[i] = a;
    }

    float r = fold8(acc, lane);

    __shared__ float lg[NPAD];
    if (lane < 8)
        lg[slot * 8 + lane] = r;
    __syncthreads();

    // wave 0: logsumexp over 61 logits -> one line-padded atomic per block
    if (tid < 64) {
        float v  = (tid < NLOGITS) ? lg[tid] : -INFINITY;
        float p0 = lg[0];
        float m = v;
        #pragma unroll
        for (int off = 32; off > 0; off >>= 1)
            m = fmaxf(m, __shfl_down(m, off, 64));
        m = __shfl(m, 0, 64);
        float e = (tid < NLOGITS) ? __expf(v - m) : 0.0f;
        #pragma unroll
        for (int off = 32; off > 0; off >>= 1)
            e += __shfl_down(e, off, 64);
        if (tid == 0) {
            float loss = m + __logf(e) - p0;
            // 64 distinct 64B lines; ~64 adds/line spread over the whole
            // kernel -> no queue (R3's 4096-on-one-address was 62us).
            atomicAdd(&slots[(b & (NSLOT - 1)) * 16], loss);
        }
    }
}

// ---- phase 3: one tiny block: 64 slots -> mean ----
__global__ __launch_bounds__(64) void finish(
    const float* __restrict__ slots, float* __restrict__ out)
{
    const int tid = threadIdx.x;
    float s = slots[tid * 16];
    #pragma unroll
    for (int off = 32; off > 0; off >>= 1)
        s += __shfl_down(s, off, 64);
    if (tid == 0)
        out[0] = s * (1.0f / (float)NB);
}

// ---- fallback (fp32 single-kernel path) if ws too small ----
__global__ __launch_bounds__(256) void u2i_loss_f32(
    const float* __restrict__ user,
    const float* __restrict__ items,
    const int* __restrict__ negidx,
    float* __restrict__ out)
{
    const int b    = blockIdx.x;
    const int tid  = threadIdx.x;
    const int wave = tid >> 6;
    const int lane = tid & 63;

    __shared__ int   rows_s[NPAD];
    __shared__ float logits[NPAD];

    if (tid < NPAD) {
        const int* nrow = negidx + (size_t)b * NK;
        rows_s[tid] = (tid == 0 || tid > NK) ? b : nrow[tid - 1];
    }
    const float4* u4 = (const float4*)user + (size_t)b * ND4;
    float4 u0 = u4[lane];
    float4 u1 = u4[64 + lane];
    float4 u2 = u4[128 + lane];
    __syncthreads();

    const float4* it4 = (const float4*)items;
    #pragma unroll
    for (int j = 0; j < 4; ++j) {
        int ks[4];
        const float4* p[4];
        #pragma unroll
        for (int i = 0; i < 4; ++i) {
            ks[i] = wave + j * 16 + i * 4;
            p[i]  = it4 + (size_t)rows_s[ks[i]] * ND4;
        }
        float4 v0[4], v1[4], v2[4];
        #pragma unroll
        for (int i = 0; i < 4; ++i) {
            v0[i] = p[i][lane];
            v1[i] = p[i][64 + lane];
            v2[i] = p[i][128 + lane];
        }
        float acc[4];
        #pragma unroll
        for (int i = 0; i < 4; ++i) {
            float a;
            a  = u0.x * v0[i].x + u0.y * v0[i].y + u0.z * v0[i].z + u0.w * v0[i].w;
            a += u1.x * v1[i].x + u1.y * v1[i].y + u1.z * v1[i].z + u1.w * v1[i].w;
            a += u2.x * v2[i].x + u2.y * v2[i].y + u2.z * v2[i].z + u2.w * v2[i].w;
            acc[i] = a;
        }
        #pragma unroll
        for (int off = 32; off > 0; off >>= 1) {
            #pragma unroll
            for (int i = 0; i < 4; ++i)
                acc[i] += __shfl_down(acc[i], off, 64);
        }
        if (lane == 0) {
            #pragma unroll
            for (int i = 0; i < 4; ++i)
                logits[ks[i]] = acc[i];
        }
    }
    __syncthreads();

    if (tid < 64) {
        float v = (tid < NLOGITS) ? logits[tid] : -INFINITY;
        float m = v;
        #pragma unroll
        for (int off = 32; off > 0; off >>= 1)
            m = fmaxf(m, __shfl_down(m, off, 64));
        m = __shfl(m, 0, 64);
        float e = (tid < NLOGITS) ? __expf(v - m) : 0.0f;
        #pragma unroll
        for (int off = 32; off > 0; off >>= 1)
            e += __shfl_down(e, off, 64);
        if (tid == 0) {
            float loss = m + __logf(e) - logits[0];
            atomicAdd(out, loss * (1.0f / (float)NB));
        }
    }
}

extern "C" void kernel_launch(void* const* d_in, const int* in_sizes, int n_in,
                              void* d_out, int out_size, void* d_ws, size_t ws_size,
                              hipStream_t stream) {
    const float* user  = (const float*)d_in[0];   // (B, D) fp32
    const float* items = (const float*)d_in[1];   // (B, D) fp32
    const int*   negi  = (const int*)d_in[2];     // (B, K) int32
    float* out = (float*)d_out;                   // scalar fp32

    if (ws_size >= WS_NEED) {
        char* ws = (char*)d_ws;
        unsigned int* itemsh = (unsigned int*)(ws + WS_ITEMS_OFF);
        unsigned int* userh  = (unsigned int*)(ws + WS_USER_OFF);
        float*        slots  = (float*)(ws + WS_SLOTS_OFF);

        // 2 x 786432 float4 -> 6144 blocks of 256
        convert_all_f16<<<2 * (NB * ND / 4) / 256, 256, 0, stream>>>(
            (const f4v*)items, (const f4v*)user,
            (uint2*)itemsh, (uint2*)userh, slots);
        // one 8-wave block per row; gather + LSE + padded-slot atomic
        gather_lse_fused<<<NB, 512, 0, stream>>>(
            userh, itemsh, negi, slots);
        finish<<<1, 64, 0, stream>>>(slots, out);
    } else {
        hipMemsetAsync(out, 0, sizeof(float), stream);
        u2i_loss_f32<<<NB, 256, 0, stream>>>(user, items, negi, out);
    }
}

// Round 9
// 119.650 us; speedup vs baseline: 1.0309x; 1.0309x over previous
//
#include <hip/hip_runtime.h>
#include <hip/hip_fp16.h>
#include <math.h>

// B=4096, D=768, K=60. Output: scalar fp32 mean CE loss, label 0.
// loss_b = logsumexp(logits_b) - logits_b[0].
//
// Ledger: R0 103.4 / R2 104.7 (2-plane split 4.0+2.0MB: null -- plane A
// == L2 size, zero slack) / R3 134.8 (atomic queue 62us) / R4 106.5
// (sched_barrier null) / R5 698.8 (coop) / R6 113.3 (LDS-DMA) /
// R7 103.6 (3-disp fused; best) / R8 123.3 (NT-on-gather HURTS -8us;
// occupancy lever was a misread of R3's drain tail).
//
// Theory: gather serves 383 MB at ~10 TB/s because the 6.3 MB table
// permanently thrashes the 4 MiB per-XCD L2. Fix: THREE 256-dim planes
// of 2.1 MB (53% of L2, real slack), one gather pass per plane, with the
// plane protected: user rows NT (single-use stream), items cached.
//
//   1. convert_planes: items fp32 -> 3 fp16 planes; user fp32 -> fp16
//      rows; block 0 zeroes the 64 padded loss slots.
//   2. gather_pass<0>/<1>: one 512-thr block per row; 61 x 512B plane
//      gathers; fold8; partial logits += in ws.
//   3. gather_pass2_lse: plane 2 + add partials + wave-0 LSE ->
//      padded-slot atomicAdd (R7's proven tail).
//   4. finish: 64 slots -> mean.

#define NB 4096
#define ND 768
#define NK 60
#define ND4  (ND / 4)          // 192 float4 per fp32 row
#define NLOGITS (NK + 1)       // 61
#define NPAD 64

#define NSLOT 64               // loss accumulator slots, one 64B line each
#define PLN_U2 ((size_t)NB * 64)   // uint2 per plane (512 B per row)

#define WS_PLANES_OFF 0                                       // 3 x 2.1 MB
#define WS_USER_OFF   ((size_t)3 * NB * 512)                  // +6.29 MB
#define WS_LOGP_OFF   (WS_USER_OFF + (size_t)NB * ND * 2)     // +6.29 MB
#define WS_SLOTS_OFF  (WS_LOGP_OFF + (size_t)NB * NPAD * 4)   // +1 MB
#define WS_NEED       (WS_SLOTS_OFF + (size_t)NSLOT * 16 * 4)

typedef _Float16 h2 __attribute__((ext_vector_type(2)));
typedef float    f2 __attribute__((ext_vector_type(2)));
typedef float    f4v __attribute__((ext_vector_type(4)));
typedef unsigned int u2v __attribute__((ext_vector_type(2)));

__device__ __forceinline__ float dot2_acc(unsigned int u, unsigned int v, float c) {
#if __has_builtin(__builtin_amdgcn_fdot2)
    return __builtin_amdgcn_fdot2(__builtin_bit_cast(h2, u),
                                  __builtin_bit_cast(h2, v), c, false);
#else
    f2 a = __builtin_convertvector(__builtin_bit_cast(h2, u), f2);
    f2 b = __builtin_convertvector(__builtin_bit_cast(h2, v), f2);
    return c + a.x * b.x + a.y * b.y;
#endif
}

__device__ __forceinline__ unsigned int pack_h2(float x, float y) {
    h2 h = { (_Float16)x, (_Float16)y };
    return __builtin_bit_cast(unsigned int, h);
}

// Butterfly fold: 8 per-lane partials -> every lane holds the full 64-lane
// sum of logit (lane & 7).  (Verified: absmax 0 in all passing rounds.)
__device__ __forceinline__ float fold8(const float acc[8], int lane) {
    const int bit0 = lane & 1;
    float n[4];
    #pragma unroll
    for (int j = 0; j < 4; ++j) {
        float mine  = bit0 ? acc[2*j+1] : acc[2*j];
        float other = bit0 ? acc[2*j]   : acc[2*j+1];
        n[j] = mine + __shfl_xor(other, 1, 64);
    }
    const int bit1 = (lane >> 1) & 1;
    float s[2];
    #pragma unroll
    for (int j = 0; j < 2; ++j) {
        float mine  = bit1 ? n[2*j+1] : n[2*j];
        float other = bit1 ? n[2*j]   : n[2*j+1];
        s[j] = mine + __shfl_xor(other, 2, 64);
    }
    const int bit2 = (lane >> 2) & 1;
    float mine  = bit2 ? s[1] : s[0];
    float other = bit2 ? s[0] : s[1];
    float r = mine + __shfl_xor(other, 4, 64);
    r += __shfl_xor(r, 8, 64);
    r += __shfl_xor(r, 16, 64);
    r += __shfl_xor(r, 32, 64);
    return r;
}

// ---- phase 1: items fp32 -> 3 planes; user fp32 -> fp16; zero slots ----
__global__ __launch_bounds__(256) void convert_planes(
    const f4v* __restrict__ items,
    const f4v* __restrict__ user,
    uint2* __restrict__ planes,
    uint2* __restrict__ userh,
    float* __restrict__ slots)
{
    const int half = NB * ND4;                  // 786432 float4 per table
    int i = blockIdx.x * 256 + threadIdx.x;

    if (blockIdx.x == 0) {
        // zero 64 padded slots (64 x 16 floats = 1024 floats = 256 float4)
        ((float4*)slots)[threadIdx.x] = make_float4(0.f, 0.f, 0.f, 0.f);
    }

    if (i < half) {
        f4v v = __builtin_nontemporal_load(items + i);
        uint2 rv;
        rv.x = pack_h2(v.x, v.y);
        rv.y = pack_h2(v.z, v.w);
        int row = i / ND4;
        int d4  = i - row * ND4;                // 0..191
        int p   = d4 >> 6;                      // plane 0..2
        int off = d4 & 63;                      // uint2 within plane row
        planes[(size_t)p * PLN_U2 + (size_t)row * 64 + off] = rv;
    } else {
        int j = i - half;
        f4v v = __builtin_nontemporal_load(user + j);
        uint2 rv;
        rv.x = pack_h2(v.x, v.y);
        rv.y = pack_h2(v.z, v.w);
        userh[j] = rv;
    }
}

// ---- gather pass core: 61 x 512B plane gathers for one row ----
// userh2: user table as uint2 (row stride 192); useg = P*64 offset.
template<int P, bool FIRST>
__global__ __launch_bounds__(512) void gather_pass(
    const uint2* __restrict__ userh2,
    const uint2* __restrict__ plane,
    const int* __restrict__ negidx,
    float* __restrict__ logp)
{
    const int tid  = threadIdx.x;
    const int lane = tid & 63;
    const int slot = tid >> 6;          // wave id, 0..7
    const int b    = blockIdx.x;

    const int* nrow = negidx + (size_t)b * NK;
    int rows[8];
    #pragma unroll
    for (int i = 0; i < 8; ++i) {
        int k = slot * 8 + i;
        rows[i] = (k == 0 || k > NK) ? b : nrow[k - 1];
    }

    // user segment: dims P*256+4l .. +3 -- NT (single-use stream; keep
    // it OUT of L2 so the plane stays resident). R8 lesson: NT belongs
    // on streams, never on the gathered table.
    u2v uv = __builtin_nontemporal_load(
        (const u2v*)(userh2 + (size_t)b * 192 + P * 64) + lane);

    // 8 plane-row gathers, cached (L2-resident plane is the whole point)
    uint2 va[8];
    #pragma unroll
    for (int i = 0; i < 8; ++i)
        va[i] = plane[(size_t)rows[i] * 64 + lane];

    float acc[8];
    #pragma unroll
    for (int i = 0; i < 8; ++i) {
        float a = dot2_acc(uv.x, va[i].x, 0.0f);
        acc[i]  = dot2_acc(uv.y, va[i].y, a);
    }

    float r = fold8(acc, lane);
    if (lane < 8) {
        size_t idx = (size_t)b * NPAD + slot * 8 + lane;
        logp[idx] = FIRST ? r : logp[idx] + r;
    }
}

// ---- pass 2 + fused LSE + padded-slot atomic ----
__global__ __launch_bounds__(512) void gather_pass2_lse(
    const uint2* __restrict__ userh2,
    const uint2* __restrict__ plane,
    const int* __restrict__ negidx,
    const float* __restrict__ logp,
    float* __restrict__ slots)
{
    const int tid  = threadIdx.x;
    const int lane = tid & 63;
    const int slot = tid >> 6;
    const int b    = blockIdx.x;

    const int* nrow = negidx + (size_t)b * NK;
    int rows[8];
    #pragma unroll
    for (int i = 0; i < 8; ++i) {
        int k = slot * 8 + i;
        rows[i] = (k == 0 || k > NK) ? b : nrow[k - 1];
    }

    u2v uv = __builtin_nontemporal_load(
        (const u2v*)(userh2 + (size_t)b * 192 + 2 * 64) + lane);

    uint2 va[8];
    #pragma unroll
    for (int i = 0; i < 8; ++i)
        va[i] = plane[(size_t)rows[i] * 64 + lane];

    float acc[8];
    #pragma unroll
    for (int i = 0; i < 8; ++i) {
        float a = dot2_acc(uv.x, va[i].x, 0.0f);
        acc[i]  = dot2_acc(uv.y, va[i].y, a);
    }

    float r = fold8(acc, lane);

    __shared__ float lg[NPAD];
    float part = logp[(size_t)b * NPAD + slot * 8 + (lane & 7)];
    if (lane < 8)
        lg[slot * 8 + lane] = r + part;
    __syncthreads();

    if (tid < 64) {
        float v  = (tid < NLOGITS) ? lg[tid] : -INFINITY;
        float p0 = lg[0];
        float m = v;
        #pragma unroll
        for (int off = 32; off > 0; off >>= 1)
            m = fmaxf(m, __shfl_down(m, off, 64));
        m = __shfl(m, 0, 64);
        float e = (tid < NLOGITS) ? __expf(v - m) : 0.0f;
        #pragma unroll
        for (int off = 32; off > 0; off >>= 1)
            e += __shfl_down(e, off, 64);
        if (tid == 0) {
            float loss = m + __logf(e) - p0;
            // 64 distinct 64B lines; ~64 adds/line spread over the whole
            // kernel -> no queue (R3's single-address was 62us).
            atomicAdd(&slots[(b & (NSLOT - 1)) * 16], loss);
        }
    }
}

// ---- phase 4: one tiny block: 64 slots -> mean ----
__global__ __launch_bounds__(64) void finish(
    const float* __restrict__ slots, float* __restrict__ out)
{
    const int tid = threadIdx.x;
    float s = slots[tid * 16];
    #pragma unroll
    for (int off = 32; off > 0; off >>= 1)
        s += __shfl_down(s, off, 64);
    if (tid == 0)
        out[0] = s * (1.0f / (float)NB);
}

// ---- fallback (fp32 single-kernel path) if ws too small ----
__global__ __launch_bounds__(256) void u2i_loss_f32(
    const float* __restrict__ user,
    const float* __restrict__ items,
    const int* __restrict__ negidx,
    float* __restrict__ out)
{
    const int b    = blockIdx.x;
    const int tid  = threadIdx.x;
    const int wave = tid >> 6;
    const int lane = tid & 63;

    __shared__ int   rows_s[NPAD];
    __shared__ float logits[NPAD];

    if (tid < NPAD) {
        const int* nrow = negidx + (size_t)b * NK;
        rows_s[tid] = (tid == 0 || tid > NK) ? b : nrow[tid - 1];
    }
    const float4* u4 = (const float4*)user + (size_t)b * ND4;
    float4 u0 = u4[lane];
    float4 u1 = u4[64 + lane];
    float4 u2 = u4[128 + lane];
    __syncthreads();

    const float4* it4 = (const float4*)items;
    #pragma unroll
    for (int j = 0; j < 4; ++j) {
        int ks[4];
        const float4* p[4];
        #pragma unroll
        for (int i = 0; i < 4; ++i) {
            ks[i] = wave + j * 16 + i * 4;
            p[i]  = it4 + (size_t)rows_s[ks[i]] * ND4;
        }
        float4 v0[4], v1[4], v2[4];
        #pragma unroll
        for (int i = 0; i < 4; ++i) {
            v0[i] = p[i][lane];
            v1[i] = p[i][64 + lane];
            v2[i] = p[i][128 + lane];
        }
        float acc[4];
        #pragma unroll
        for (int i = 0; i < 4; ++i) {
            float a;
            a  = u0.x * v0[i].x + u0.y * v0[i].y + u0.z * v0[i].z + u0.w * v0[i].w;
            a += u1.x * v1[i].x + u1.y * v1[i].y + u1.z * v1[i].z + u1.w * v1[i].w;
            a += u2.x * v2[i].x + u2.y * v2[i].y + u2.z * v2[i].z + u2.w * v2[i].w;
            acc[i] = a;
        }
        #pragma unroll
        for (int off = 32; off > 0; off >>= 1) {
            #pragma unroll
            for (int i = 0; i < 4; ++i)
                acc[i] += __shfl_down(acc[i], off, 64);
        }
        if (lane == 0) {
            #pragma unroll
            for (int i = 0; i < 4; ++i)
                logits[ks[i]] = acc[i];
        }
    }
    __syncthreads();

    if (tid < 64) {
        float v = (tid < NLOGITS) ? logits[tid] : -INFINITY;
        float m = v;
        #pragma unroll
        for (int off = 32; off > 0; off >>= 1)
            m = fmaxf(m, __shfl_down(m, off, 64));
        m = __shfl(m, 0, 64);
        float e = (tid < NLOGITS) ? __expf(v - m) : 0.0f;
        #pragma unroll
        for (int off = 32; off > 0; off >>= 1)
            e += __shfl_down(e, off, 64);
        if (tid == 0) {
            float loss = m + __logf(e) - logits[0];
            atomicAdd(out, loss * (1.0f / (float)NB));
        }
    }
}

extern "C" void kernel_launch(void* const* d_in, const int* in_sizes, int n_in,
                              void* d_out, int out_size, void* d_ws, size_t ws_size,
                              hipStream_t stream) {
    const float* user  = (const float*)d_in[0];   // (B, D) fp32
    const float* items = (const float*)d_in[1];   // (B, D) fp32
    const int*   negi  = (const int*)d_in[2];     // (B, K) int32
    float* out = (float*)d_out;                   // scalar fp32

    if (ws_size >= WS_NEED) {
        char* ws = (char*)d_ws;
        uint2* planes = (uint2*)(ws + WS_PLANES_OFF);
        uint2* userh2 = (uint2*)(ws + WS_USER_OFF);
        float* logp   = (float*)(ws + WS_LOGP_OFF);
        float* slots  = (float*)(ws + WS_SLOTS_OFF);

        // 2 x 786432 float4 -> 6144 blocks of 256
        convert_planes<<<2 * (NB * ND4) / 256, 256, 0, stream>>>(
            (const f4v*)items, (const f4v*)user, planes, userh2, slots);
        // three gather passes, each against a 2.1 MB L2-resident plane
        gather_pass<0, true ><<<NB, 512, 0, stream>>>(
            userh2, planes,              negi, logp);
        gather_pass<1, false><<<NB, 512, 0, stream>>>(
            userh2, planes + PLN_U2,     negi, logp);
        gather_pass2_lse<<<NB, 512, 0, stream>>>(
            userh2, planes + 2 * PLN_U2, negi, logp, slots);
        finish<<<1, 64, 0, stream>>>(slots, out);
    } else {
        hipMemsetAsync(out, 0, sizeof(float), stream);
        u2i_loss_f32<<<NB, 256, 0, stream>>>(user, items, negi, out);
    }
}